// Round 6
// baseline (283.538 us; speedup 1.0000x reference)
//
#include <hip/hip_runtime.h>
#include <hip/hip_bf16.h>
#include <math.h>

// Problem constants
#define NN 32768
#define CC 512
#define AA 64
#define CIN 1024
#define EPSV 1e-7f

// All inputs/outputs are FLOAT32 (reference dtype).
//
// Workspace layout (floats) — every slot written before read (0xAA-poison safe):
//   pd[8][1604]  : [0,12832)  per-chunk GEMV partials. Rows 0..575: W_query;
//                  576..1087: W_erase; 1088..1599: W_content_hidden;
//                  1600: ush·h, 1601: ulr·h, 1602: uca·[h;x]; 1603 pad.
//   contx[512]   : [12832,13344)  W_content_input @ x (direct)
//   stats[1536]  : [13344,14880)  m_b[512], Zl[512], S2l[512]
//   pa[64][512]  : [14880,47648)  A-col partials (pa[j*512+blk])
//   pm[1024][512]: [47648,571936) M-col partials (e<512: w·M, e>=512: w²·M)

#define PDS   1604
#define CXOFF 12832
#define STOFF 13344
#define PAOFF 14880
#define PMOFF 47648

typedef float floatx4 __attribute__((ext_vector_type(4)));

__device__ __forceinline__ float4 ntload4(const float4* p) {
    floatx4 v = __builtin_nontemporal_load(reinterpret_cast<const floatx4*>(p));
    return make_float4(v.x, v.y, v.z, v.w);
}
__device__ __forceinline__ float ntloadf(const float* p) {
    return __builtin_nontemporal_load(p);
}

// ---------------- K1q: W_query rows + ush/ulr dots ------------------------
// grid 592 x 256. b<576: rg=b>>3 (8 rows of Wq), chunk=b&7 (4096 cols),
// h chunk in LDS, 4 waves split the chunk, write pd[chunk][row].
// b>=576: t=b-576, sd=t>>3 in {0,1} (ush/ulr), chunk=t&7 -> pd[chunk][1600+sd].
__global__ __launch_bounds__(256) void k1q(
    const float* __restrict__ h, const float* __restrict__ Wq,
    const float* __restrict__ ush, const float* __restrict__ ulr,
    float* __restrict__ ws)
{
    __shared__ float hs[4096];
    __shared__ float red[4][8];
    const int b = blockIdx.x, tid = threadIdx.x;
    const int wave = tid >> 6, lane = tid & 63;

    if (b < 576) {
        const int rg = b >> 3, chunk = b & 7;
        const float4* h4 = reinterpret_cast<const float4*>(h) + chunk * 1024;
        float4* hs4 = reinterpret_cast<float4*>(hs);
        #pragma unroll
        for (int k = 0; k < 4; ++k) hs4[k * 256 + tid] = h4[k * 256 + tid];
        __syncthreads();
        const int r0 = rg * 8;
        const float4* m4 = reinterpret_cast<const float4*>(
            Wq + (size_t)r0 * NN + chunk * 4096);
        const int rs = NN / 4;
        float acc[8] = {0,0,0,0,0,0,0,0};
        float4 cur[8];
        #pragma unroll
        for (int r = 0; r < 8; ++r) cur[r] = ntload4(m4 + (size_t)r * rs + tid);
        #pragma unroll
        for (int it = 0; it < 4; ++it) {
            float4 nxt[8];
            if (it < 3) {
                #pragma unroll
                for (int r = 0; r < 8; ++r)
                    nxt[r] = ntload4(m4 + (size_t)r * rs + (it + 1) * 256 + tid);
            }
            float4 hb = hs4[it * 256 + tid];
            #pragma unroll
            for (int r = 0; r < 8; ++r)
                acc[r] += cur[r].x * hb.x + cur[r].y * hb.y +
                          cur[r].z * hb.z + cur[r].w * hb.w;
            if (it < 3) {
                #pragma unroll
                for (int r = 0; r < 8; ++r) cur[r] = nxt[r];
            }
        }
        #pragma unroll
        for (int r = 0; r < 8; ++r) {
            #pragma unroll
            for (int off = 32; off >= 1; off >>= 1)
                acc[r] += __shfl_xor(acc[r], off);
        }
        if (lane == 0) {
            #pragma unroll
            for (int r = 0; r < 8; ++r) red[wave][r] = acc[r];
        }
        __syncthreads();
        if (tid < 8) {
            float v = red[0][tid] + red[1][tid] + red[2][tid] + red[3][tid];
            ws[chunk * PDS + r0 + tid] = v;
        }
    } else {
        const int t = b - 576, sd = t >> 3, chunk = t & 7;
        const float* vec = sd ? ulr : ush;
        const float4* v4 = reinterpret_cast<const float4*>(vec) + chunk * 1024;
        const float4* h4 = reinterpret_cast<const float4*>(h) + chunk * 1024;
        float acc = 0.f;
        #pragma unroll
        for (int it = 0; it < 4; ++it) {
            float4 a = v4[it * 256 + tid];
            float4 hb = h4[it * 256 + tid];
            acc += a.x * hb.x + a.y * hb.y + a.z * hb.z + a.w * hb.w;
        }
        #pragma unroll
        for (int off = 32; off >= 1; off >>= 1)
            acc += __shfl_xor(acc, off);
        if (lane == 0) red[wave][0] = acc;
        __syncthreads();
        if (tid == 0)
            ws[chunk * PDS + 1600 + sd] =
                red[0][0] + red[1][0] + red[2][0] + red[3][0];
    }
}

// ---------------- K2big: fused M/A online-softmax pass + remaining GEMVs --
// grid 1608 x 512 (8 waves). Block g:
//   g<1024      : Wer/Wch rows 576..1599. rg=g>>3, chunk=g&7. One row per
//                 wave (16 float4/lane), h chunk in LDS -> pd[chunk][row].
//   g<1088      : Wci rows (8/block, one per wave) -> contx[row].
//   g<1096      : uca chunk dot (chunk 0 adds x-tail) -> pd[chunk][1602].
//   g<1608      : M-block b=g-1096 — online-softmax over rows [b*64,b*64+64),
//                 q rebuilt from pd partials in LDS; emits pm/pa/stats.
__global__ __launch_bounds__(512) void k2big(
    const float* __restrict__ h, const float* __restrict__ x,
    const float* __restrict__ Wer, const float* __restrict__ Wch,
    const float* __restrict__ Wci, const float* __restrict__ uca,
    const float* __restrict__ Mm, const float* __restrict__ Ad,
    const float* __restrict__ ema,
    const float* __restrict__ bq, const float* __restrict__ bsh,
    const float* __restrict__ blr,
    float* __restrict__ ws)
{
    __shared__ float smem[8736];   // union: hs[4096] | qs[576]+red[512]+sc[3] | lw[8][1092]
    const int g = blockIdx.x, tid = threadIdx.x;
    const int wave = tid >> 6, lane = tid & 63;
    float* contx = ws + CXOFF;
    float* stats = ws + STOFF;
    float* pa = ws + PAOFF;
    float* pm = ws + PMOFF;

    if (g < 1024) {
        const int rg = g >> 3, chunk = g & 7;
        const int r = 576 + rg * 8 + wave;
        const float4* h4 = reinterpret_cast<const float4*>(h) + chunk * 1024;
        float4* hs4 = reinterpret_cast<float4*>(smem);
        hs4[tid] = h4[tid];
        hs4[tid + 512] = h4[tid + 512];
        __syncthreads();
        const float* mat = (r < 1088) ? Wer : Wch;
        const int base = (r < 1088) ? 576 : 1088;
        const float4* m4 = reinterpret_cast<const float4*>(
            mat + (size_t)(r - base) * NN + chunk * 4096);
        float acc = 0.f;
        #pragma unroll
        for (int it = 0; it < 16; ++it) {
            float4 a = ntload4(m4 + it * 64 + lane);
            float4 hb = hs4[it * 64 + lane];
            acc += a.x * hb.x + a.y * hb.y + a.z * hb.z + a.w * hb.w;
        }
        #pragma unroll
        for (int off = 32; off >= 1; off >>= 1)
            acc += __shfl_xor(acc, off);
        if (lane == 0) ws[chunk * PDS + r] = acc;
    } else if (g < 1088) {
        const int wg = g - 1024;
        const int r = wg * 8 + wave;
        float4* hs4 = reinterpret_cast<float4*>(smem);
        if (tid < 256) hs4[tid] = reinterpret_cast<const float4*>(x)[tid];
        __syncthreads();
        const float4* m4 = reinterpret_cast<const float4*>(Wci + (size_t)r * CIN);
        float acc = 0.f;
        #pragma unroll
        for (int it = 0; it < 4; ++it) {
            float4 a = ntload4(m4 + it * 64 + lane);
            float4 hb = hs4[it * 64 + lane];
            acc += a.x * hb.x + a.y * hb.y + a.z * hb.z + a.w * hb.w;
        }
        #pragma unroll
        for (int off = 32; off >= 1; off >>= 1)
            acc += __shfl_xor(acc, off);
        if (lane == 0) contx[r] = acc;
    } else if (g < 1096) {
        const int chunk = g - 1088;
        const float4* u4 = reinterpret_cast<const float4*>(uca) + chunk * 1024;
        const float4* h4 = reinterpret_cast<const float4*>(h) + chunk * 1024;
        float acc = 0.f;
        {
            float4 a = u4[tid], hb = h4[tid];
            acc += a.x * hb.x + a.y * hb.y + a.z * hb.z + a.w * hb.w;
            a = u4[tid + 512]; hb = h4[tid + 512];
            acc += a.x * hb.x + a.y * hb.y + a.z * hb.z + a.w * hb.w;
        }
        if (chunk == 0 && tid < 256) {
            float4 a = reinterpret_cast<const float4*>(uca)[NN / 4 + tid];
            float4 xv = reinterpret_cast<const float4*>(x)[tid];
            acc += a.x * xv.x + a.y * xv.y + a.z * xv.z + a.w * xv.w;
        }
        smem[tid] = acc; __syncthreads();
        for (int st = 256; st > 0; st >>= 1) {
            if (tid < st) smem[tid] += smem[tid + st];
            __syncthreads();
        }
        if (tid == 0) ws[chunk * PDS + 1602] = smem[0];
    } else {
        const int b = g - 1096;
        float* qs  = smem;          // [0,576)
        float* red = smem + 576;    // [576,1088)
        float* scl = smem + 1088;   // qn, beta, gamma
        // phase 0: rebuild q from chunk partials; qnorm; beta/gamma
        float sq = 0.f;
        for (int j = tid; j < 576; j += 512) {
            float q = bq[j];
            #pragma unroll
            for (int ch = 0; ch < 8; ++ch) q += ws[ch * PDS + j];
            qs[j] = q; sq += q * q;
        }
        red[tid] = sq; __syncthreads();
        for (int st = 256; st > 0; st >>= 1) {
            if (tid < st) red[tid] += red[tid + st];
            __syncthreads();
        }
        if (tid == 0) {
            scl[0] = fmaxf(sqrtf(red[0]), EPSV);
            float sb = bsh[0], sl = blr[0];
            #pragma unroll
            for (int ch = 0; ch < 8; ++ch) {
                sb += ws[ch * PDS + 1600];
                sl += ws[ch * PDS + 1601];
            }
            scl[1] = (sb > 20.f ? sb : log1pf(expf(sb))) + 1.0f; // beta
            scl[2] = 1.f / (1.f + expf(-sl));                    // gamma
        }
        __syncthreads();
        const float qn = scl[0], beta = scl[1], gamma = scl[2];
        const float ql = qs[lane];
        float4 qa = *reinterpret_cast<const float4*>(qs + 64 + lane * 8);
        float4 qb2 = *reinterpret_cast<const float4*>(qs + 68 + lane * 8);
        float qm[8] = {qa.x, qa.y, qa.z, qa.w, qb2.x, qb2.y, qb2.z, qb2.w};
        __syncthreads();   // all qs reads done before smem reuse as lw

        float a1[8] = {0,0,0,0,0,0,0,0};
        float a2[8] = {0,0,0,0,0,0,0,0};
        float aA = 0.f, m_run = -1e30f, Z = 0.f, S2 = 0.f;
        const int base = b * 64 + wave * 8;
        for (int j = 0; j < 8; ++j) {
            const int i = base + j;
            float a = ntloadf(Ad + (size_t)i * AA + lane);
            float4 m0 = ntload4(reinterpret_cast<const float4*>(Mm + (size_t)i * CC + lane * 8));
            float4 m1 = ntload4(reinterpret_cast<const float4*>(Mm + (size_t)i * CC + lane * 8 + 4));
            float mm[8] = {m0.x, m0.y, m0.z, m0.w, m1.x, m1.y, m1.z, m1.w};
            float dot = a * ql, nn = a * a;
            #pragma unroll
            for (int k = 0; k < 8; ++k) { float f = mm[k]; dot += f * qm[k]; nn += f * f; }
            #pragma unroll
            for (int off = 32; off >= 1; off >>= 1) {
                dot += __shfl_xor(dot, off);
                nn  += __shfl_xor(nn, off);
            }
            float mn = fmaxf(sqrtf(nn), EPSV);
            float s = beta * (dot / (mn * qn)) - gamma * ema[i];
            if (s > m_run) {                 // wave-uniform branch
                float f = expf(m_run - s);   // 0 on first row
                float f2 = f * f;
                Z *= f; S2 *= f2; aA *= f;
                #pragma unroll
                for (int k = 0; k < 8; ++k) { a1[k] *= f; a2[k] *= f2; }
                m_run = s;
            }
            float w = expf(s - m_run);
            float w2 = w * w;
            Z += w; S2 += w2; aA += w * a;
            #pragma unroll
            for (int k = 0; k < 8; ++k) { a1[k] += w * mm[k]; a2[k] += w2 * mm[k]; }
        }
        float* lw = smem;  // lw[wave] at smem + wave*1092
        float* mylw = lw + wave * 1092;
        #pragma unroll
        for (int k = 0; k < 8; ++k) {
            mylw[lane * 8 + k] = a1[k];
            mylw[512 + lane * 8 + k] = a2[k];
        }
        mylw[1024 + lane] = aA;
        if (lane == 0) { mylw[1088] = m_run; mylw[1089] = Z; mylw[1090] = S2; }
        __syncthreads();
        float mb = lw[1088];
        #pragma unroll
        for (int w = 1; w < 8; ++w) mb = fmaxf(mb, lw[w * 1092 + 1088]);
        float fw[8];
        #pragma unroll
        for (int w = 0; w < 8; ++w) fw[w] = expf(lw[w * 1092 + 1088] - mb);
        for (int e = tid; e < 1024; e += 512) {
            float v = 0.f;
            if (e < 512) {
                #pragma unroll
                for (int w = 0; w < 8; ++w) v += fw[w] * lw[w * 1092 + e];
            } else {
                #pragma unroll
                for (int w = 0; w < 8; ++w) v += fw[w] * fw[w] * lw[w * 1092 + e];
            }
            pm[(size_t)e * 512 + b] = v;
        }
        if (tid < 64) {
            float v = 0.f;
            #pragma unroll
            for (int w = 0; w < 8; ++w) v += fw[w] * lw[w * 1092 + 1024 + tid];
            pa[tid * 512 + b] = v;
        }
        if (tid == 0) {
            float Zl = 0.f, S2l = 0.f;
            #pragma unroll
            for (int w = 0; w < 8; ++w) {
                Zl  += fw[w] * lw[w * 1092 + 1089];
                S2l += fw[w] * fw[w] * lw[w * 1092 + 1090];
            }
            stats[b] = mb; stats[512 + b] = Zl; stats[1024 + b] = S2l;
        }
    }
}

// ---------------- K5: global stats (per-block recompute) + epilogue -------
// grid 576 x 256: b<64 -> out[b]; else c=b-64 -> out[64+c]
__global__ __launch_bounds__(256) void k5_final(
    const float* __restrict__ ws, const float* __restrict__ ber,
    const float* __restrict__ bca, float* __restrict__ out)
{
    __shared__ float red[256];
    __shared__ float bc[2];
    const int b = blockIdx.x, tid = threadIdx.x;
    const float* stats = ws + STOFF;
    const float* pa = ws + PAOFF;
    const float* pm = ws + PMOFF;
    const float* contx = ws + CXOFF;

    // global max over stats[0..512)
    float m = fmaxf(stats[tid], stats[tid + 256]);
    red[tid] = m; __syncthreads();
    for (int st = 128; st > 0; st >>= 1) {
        if (tid < st) red[tid] = fmaxf(red[tid], red[tid + st]);
        __syncthreads();
    }
    if (tid == 0) bc[0] = red[0];
    __syncthreads();
    const float mx = bc[0];
    const float e1a = expf(stats[tid] - mx);
    const float e1b = expf(stats[tid + 256] - mx);
    // Zg
    red[tid] = e1a * stats[512 + tid] + e1b * stats[512 + tid + 256];
    __syncthreads();
    for (int st = 128; st > 0; st >>= 1) {
        if (tid < st) red[tid] += red[tid + st];
        __syncthreads();
    }
    const float Zg = red[0];
    __syncthreads();
    // S2 sum
    red[tid] = e1a * e1a * stats[1024 + tid] + e1b * e1b * stats[1024 + tid + 256];
    __syncthreads();
    for (int st = 128; st > 0; st >>= 1) {
        if (tid < st) red[tid] += red[tid + st];
        __syncthreads();
    }
    const float iZ = 1.f / Zg;
    const float S2g = red[0] * iZ * iZ;
    __syncthreads();

    if (b < 64) {
        red[tid] = e1a * pa[b * 512 + tid] + e1b * pa[b * 512 + tid + 256];
        __syncthreads();
        for (int st = 128; st > 0; st >>= 1) {
            if (tid < st) red[tid] += red[tid + st];
            __syncthreads();
        }
        if (tid == 0) out[b] = iZ * red[0];
    } else {
        const int c = b - 64;
        float v1 = e1a * pm[(size_t)c * 512 + tid]
                 + e1b * pm[(size_t)c * 512 + tid + 256];
        float v2 = e1a * e1a * pm[(size_t)(512 + c) * 512 + tid]
                 + e1b * e1b * pm[(size_t)(512 + c) * 512 + tid + 256];
        red[tid] = v1; __syncthreads();
        for (int st = 128; st > 0; st >>= 1) {
            if (tid < st) red[tid] += red[tid + st];
            __syncthreads();
        }
        const float s1 = iZ * red[0];
        __syncthreads();
        red[tid] = v2; __syncthreads();
        for (int st = 128; st > 0; st >>= 1) {
            if (tid < st) red[tid] += red[tid + st];
            __syncthreads();
        }
        if (tid == 0) {
            const float s2v = iZ * iZ * red[0];
            float er = ber[c], chv = 0.f, alpha = bca[0];
            #pragma unroll
            for (int ch = 0; ch < 8; ++ch) {
                er    += ws[ch * PDS + 576 + c];
                chv   += ws[ch * PDS + 1088 + c];
                alpha += ws[ch * PDS + 1602];
            }
            const float cand = fmaxf(chv + alpha * contx[c], 0.f);
            out[64 + c] = s1 - er * s2v + S2g * cand;
        }
    }
}

extern "C" void kernel_launch(void* const* d_in, const int* in_sizes, int n_in,
                              void* d_out, int out_size, void* d_ws, size_t ws_size,
                              hipStream_t stream)
{
    const float* h   = (const float*)d_in[0];
    const float* x   = (const float*)d_in[1];
    const float* Mm  = (const float*)d_in[2];
    const float* Ad  = (const float*)d_in[3];
    const float* ema = (const float*)d_in[4];
    const float* Wq  = (const float*)d_in[5];
    const float* bq  = (const float*)d_in[6];
    const float* ush = (const float*)d_in[7];
    const float* bsh = (const float*)d_in[8];
    const float* ulr = (const float*)d_in[9];
    const float* blr = (const float*)d_in[10];
    const float* Wer = (const float*)d_in[11];
    const float* ber = (const float*)d_in[12];
    const float* Wch = (const float*)d_in[13];
    const float* Wci = (const float*)d_in[14];
    const float* uca = (const float*)d_in[15];
    const float* bca = (const float*)d_in[16];

    float* ws  = (float*)d_ws;
    float* out = (float*)d_out;

    hipLaunchKernelGGL(k1q,     dim3(592),  dim3(256), 0, stream,
                       h, Wq, ush, ulr, ws);
    hipLaunchKernelGGL(k2big,   dim3(1608), dim3(512), 0, stream,
                       h, x, Wer, Wch, Wci, uca, Mm, Ad, ema, bq, bsh, blr, ws);
    hipLaunchKernelGGL(k5_final, dim3(576), dim3(256), 0, stream,
                       ws, ber, bca, out);
}